// Round 10
// baseline (132.602 us; speedup 1.0000x reference)
//
#include <hip/hip_runtime.h>

#define HID 2048
#define NE 64
#define NTOK 32768        // GROUPS * TOKENS = 4 * 8192
#define CAP 160
#define GAP_THR 0.01f

typedef unsigned short u16;
typedef short bf16x8 __attribute__((ext_vector_type(8)));
typedef float f32x16 __attribute__((ext_vector_type(16)));

typedef __attribute__((address_space(1))) const void gvoid;
typedef __attribute__((address_space(3))) void lvoid;
#define GLOAD_LDS16(gp, lp) \
    __builtin_amdgcn_global_load_lds((gvoid*)(gp), (lvoid*)(lp), 16, 0, 0)

// fp32 -> bf16 hi (truncate) + bf16 lo (truncate of exact remainder).
static __device__ __forceinline__ void cvt8(const float4& a, const float4& b,
                                            bf16x8& hi, bf16x8& lo) {
    float f[8] = {a.x, a.y, a.z, a.w, b.x, b.y, b.z, b.w};
#pragma unroll
    for (int j = 0; j < 8; ++j) {
        const unsigned u = __float_as_uint(f[j]);
        const unsigned h = u >> 16;
        const float r = f[j] - __uint_as_float(h << 16);   // exact
        hi[j] = (short)h;
        lo[j] = (short)(__float_as_uint(r) >> 16);
    }
}

// ---------------------------------------------------------------------------
// K0: split W into bf16 hi/lo, fragment-major: step S (0..127) owns 4KB
// [h0|h1|l0|l1], each chunk 1KB = lane*16B.  S = global K-step = k0/16.
// ---------------------------------------------------------------------------
__global__ void k_wconv(const float* __restrict__ W, u16* __restrict__ Wfrag)
{
    const int idx = blockIdx.x * 256 + threadIdx.x;   // 0..16383
    if (idx >= NE * (HID / 8)) return;
    const int e  = idx >> 8;          // expert 0..63
    const int k0 = (idx & 255) * 8;
    const int S    = k0 >> 4;
    const int khal = (k0 >> 3) & 1;
    const int lane = (e & 31) + khal * 32;

    bf16x8 hi, lo;
    const float4 a = *(const float4*)(W + (size_t)e * HID + k0);
    const float4 b = *(const float4*)(W + (size_t)e * HID + k0 + 4);
    cvt8(a, b, hi, lo);

    u16* base = Wfrag + (size_t)S * 2048 + (size_t)(e >> 5) * 512 + lane * 8;
    *(bf16x8*)(base)        = hi;     // chunk (e>>5)
    *(bf16x8*)(base + 1024) = lo;     // chunk 2+(e>>5)
}

// ---------------------------------------------------------------------------
// K1: logits via 3-term bf16-split MFMA.  ROW-CONTIGUOUS A staging:
// chunk = [32 rows][256 floats] (32 KB), double-buffered (64 KB LDS,
// 2 blocks/CU).  Each DMA instr = ONE row x 1 KB contiguous (64 lanes x 16B)
// -> DRAM page-friendly runs (the round-9 post-mortem's rate limiter was
// 256-512 B runs scattered at 8 KB stride: 2.78 TB/s MSHR/page-miss ceiling).
// Source granules pre-swizzled sg^row (LDS dest linear); compute reads
// granule g^(row&7) -> 8 bank-groups, ~4-way b128 conflicts (epilog-cheap).
// W for chunk c+1 fully prefetched to registers during chunk c, issued
// AFTER DMA(c+1) so FIFO W-waits never retire the A-DMA.  Split-K: wave kq
// owns k-steps [kq*4, kq*4+4) of each chunk's 16; reduce in epilogue.
// ---------------------------------------------------------------------------
__global__ __launch_bounds__(256, 2) void k_logits(
    const float* __restrict__ A, const u16* __restrict__ Wfrag,
    const float* __restrict__ bias,
    float* __restrict__ logits, float* __restrict__ probsmax,
    int* __restrict__ choice, int* __restrict__ idx2o, float* __restrict__ gapo)
{
    __shared__ float smem[16384];         // 64 KB: 2 x [32][256]; reused as lacc
    const int tid  = threadIdx.x;
    const int lane = tid & 63;
    const int kq   = __builtin_amdgcn_readfirstlane(tid >> 6);  // 0..3 uniform
    const int tok0 = blockIdx.x * 32;
    const int trow = lane & 31;           // token row (B-col)
    const int khal = lane >> 5;

    // 8 row-source pointers: wave kq stages rows kq*8+i; lane sg holds
    // global granule sg^i of that row (i == row&7 since kq*8 is 8-aligned).
    const int sg = lane;                  // granule slot 0..63 (16B each)
#define GPDEF(i) const float* gp##i = A + (size_t)(tok0 + kq*8 + i) * HID + ((sg ^ i) << 2);
    GPDEF(0) GPDEF(1) GPDEF(2) GPDEF(3) GPDEF(4) GPDEF(5) GPDEF(6) GPDEF(7)
#undef GPDEF

    const u16* wbase = Wfrag + lane * 8;  // per-lane 16B, coalesced 1KB/instr

    f32x16 acc0, acc1;
#pragma unroll
    for (int r = 0; r < 16; ++r) { acc0[r] = 0.0f; acc1[r] = 0.0f; }

    bf16x8 wE[16], wO[16];                // W frag sets (4 substeps x h0,h1,l0,l1)

#define MFMA_ __builtin_amdgcn_mfma_f32_32x32x16_bf16
#define DMA8(BUF, C) {                                                    \
    float* d = smem + (BUF) * 8192 + kq * 2048;                           \
    GLOAD_LDS16(gp0 + (C) * 256, d);                                      \
    GLOAD_LDS16(gp1 + (C) * 256, d + 256);                                \
    GLOAD_LDS16(gp2 + (C) * 256, d + 512);                                \
    GLOAD_LDS16(gp3 + (C) * 256, d + 768);                                \
    GLOAD_LDS16(gp4 + (C) * 256, d + 1024);                               \
    GLOAD_LDS16(gp5 + (C) * 256, d + 1280);                               \
    GLOAD_LDS16(gp6 + (C) * 256, d + 1536);                               \
    GLOAD_LDS16(gp7 + (C) * 256, d + 1792); }
#define LOADW16(SET, C) {                                                 \
    _Pragma("unroll")                                                     \
    for (int sl = 0; sl < 4; ++sl) {                                      \
        const u16* wp = wbase + (size_t)((C) * 16 + kq * 4 + sl) * 2048;  \
        SET[sl*4+0] = *(const bf16x8*)(wp);                               \
        SET[sl*4+1] = *(const bf16x8*)(wp + 512);                         \
        SET[sl*4+2] = *(const bf16x8*)(wp + 1024);                        \
        SET[sl*4+3] = *(const bf16x8*)(wp + 1536);                        \
    } }
#define SUBSTEP(BUF, SET, SL) {                                           \
    const int g0 = kq * 16 + (SL) * 4 + khal * 2;                         \
    const float* bp = smem + (BUF) * 8192 + trow * 256;                   \
    const float4 va = *(const float4*)(bp + (((g0)     ^ (trow & 7)) << 2)); \
    const float4 vb = *(const float4*)(bp + (((g0 + 1) ^ (trow & 7)) << 2)); \
    bf16x8 ah, al; cvt8(va, vb, ah, al);                                  \
    acc0 = MFMA_(SET[(SL)*4+0], ah, acc0, 0, 0, 0);                       \
    acc1 = MFMA_(SET[(SL)*4+1], ah, acc1, 0, 0, 0);                       \
    acc0 = MFMA_(SET[(SL)*4+2], ah, acc0, 0, 0, 0);                       \
    acc1 = MFMA_(SET[(SL)*4+3], ah, acc1, 0, 0, 0);                       \
    acc0 = MFMA_(SET[(SL)*4+0], al, acc0, 0, 0, 0);                       \
    acc1 = MFMA_(SET[(SL)*4+1], al, acc1, 0, 0, 0); }
// entry vmcnt(16): outstanding = DMA(C):8 + W(C):16 -> waits all of DMA(C),
// leaves W(C) (compiler waits those at first MFMA use; FIFO: W(C) older than
// DMA(C+1) so those waits never stall the A pipeline).
#define ITER(C, USE, LD) {                                                \
    asm volatile("s_waitcnt vmcnt(16)" ::: "memory");                     \
    __builtin_amdgcn_s_barrier();                                         \
    __builtin_amdgcn_sched_barrier(0);                                    \
    if ((C) + 1 < 8) {                                                    \
        DMA8(((C) + 1) & 1, (C) + 1)                                      \
        __builtin_amdgcn_sched_barrier(0);                                \
        LOADW16(LD, (C) + 1)                                              \
        __builtin_amdgcn_sched_barrier(0);                                \
    }                                                                     \
    SUBSTEP((C) & 1, USE, 0)                                              \
    SUBSTEP((C) & 1, USE, 1)                                              \
    SUBSTEP((C) & 1, USE, 2)                                              \
    SUBSTEP((C) & 1, USE, 3) }

    // prologue: stage chunk 0 + its W set
    DMA8(0, 0)
    __builtin_amdgcn_sched_barrier(0);
    LOADW16(wE, 0)

    ITER(0, wE, wO) ITER(1, wO, wE) ITER(2, wE, wO) ITER(3, wO, wE)
    ITER(4, wE, wO) ITER(5, wO, wE) ITER(6, wE, wO) ITER(7, wO, wE)
#undef ITER
#undef SUBSTEP
#undef DMA8
#undef LOADW16

    __syncthreads();                      // all reads done; reuse smem as lacc

    // ---- epilogue: smem reused as lacc[4][32*65] ----
    {
        float* pl = smem + kq * 2080 + trow * 65;
#pragma unroll
        for (int r = 0; r < 16; ++r) {
            const int er = (r & 3) + 8 * (r >> 2) + 4 * khal;
            pl[er]      = acc0[r];
            pl[32 + er] = acc1[r];
        }
    }
    __syncthreads();

    // split-K reduce (+bias), coalesced logits store, stash row into plane 0
    {
        const int t  = tid >> 3;          // 0..31
        const int e0 = (tid & 7) * 8;
        float v[8];
#pragma unroll
        for (int i = 0; i < 8; ++i) {
            const int o = t * 65 + e0 + i;
            v[i] = smem[o] + smem[2080 + o] + smem[4160 + o] + smem[6240 + o]
                 + bias[e0 + i];
        }
        float* lp = logits + (size_t)(tok0 + t) * NE + e0;
        *(float4*)(lp)     = make_float4(v[0], v[1], v[2], v[3]);
        *(float4*)(lp + 4) = make_float4(v[4], v[5], v[6], v[7]);
#pragma unroll
        for (int i = 0; i < 8; ++i) smem[t * 65 + e0 + i] = v[i];
    }
    __syncthreads();

    // per-token epilogue: top-2 + softmax denominator
    if (tid < 32) {
        const int t = tid;
        float m1 = -3.4e38f, m2 = -3.4e38f;
        int i1 = 0, i2 = 0;
#pragma unroll
        for (int e = 0; e < NE; ++e) {
            const float vv = smem[t * 65 + e];
            if (vv > m1)      { m2 = m1; i2 = i1; m1 = vv; i1 = e; }
            else if (vv > m2) { m2 = vv; i2 = e; }
        }
        float sden = 0.0f;
#pragma unroll
        for (int e = 0; e < NE; ++e)
            sden += __expf(smem[t * 65 + e] - m1);
        const int g2 = tok0 + t;
        probsmax[g2] = 1.0f / sden;       // max prob = exp(0)/sum
        choice[g2]   = i1;
        idx2o[g2]    = i2;
        gapo[g2]     = m1 - m2;
    }
}

// ---------------------------------------------------------------------------
// K1b: fp64 refinement of near-tie argmax, wave-cooperative.
// ---------------------------------------------------------------------------
__global__ __launch_bounds__(64) void k_refine(
    const float* __restrict__ A, const float* __restrict__ W,
    const float* __restrict__ bias,
    int* __restrict__ choice, const int* __restrict__ idx2,
    const float* __restrict__ gap)
{
    const int lane = threadIdx.x;
    const int gt0  = blockIdx.x * 64;
    const int gtl  = gt0 + lane;
    const bool flag = (gap[gtl] < GAP_THR) && (choice[gtl] != idx2[gtl]);
    unsigned long long m = __ballot(flag);
    while (m) {
        const int t = (int)__ffsll((long long)m) - 1;
        m &= m - 1;
        const int gt = gt0 + t;
        const int i1 = choice[gt], i2 = idx2[gt];
        const float* a  = A + (size_t)gt * HID;
        const float* w1 = W + (size_t)i1 * HID;
        const float* w2 = W + (size_t)i2 * HID;
        double d1 = 0.0, d2 = 0.0;
#pragma unroll 4
        for (int h = lane; h < HID; h += 64) {
            const double av = (double)a[h];
            d1 += av * (double)w1[h];
            d2 += av * (double)w2[h];
        }
#pragma unroll
        for (int o = 32; o; o >>= 1) {
            d1 += __shfl_xor(d1, o);
            d2 += __shfl_xor(d2, o);
        }
        if (lane == 0) {
            d1 += (double)bias[i1];
            d2 += (double)bias[i2];
            if (d2 > d1 || (d2 == d1 && i2 < i1)) choice[gt] = i2;
        }
    }
}

// ---------------------------------------------------------------------------
// K2: per-64-token-chunk histogram of expert choices (wave ballot).
// ---------------------------------------------------------------------------
__global__ void k_count(const int* __restrict__ choice, int* __restrict__ cnt)
{
    const int lane  = threadIdx.x & 63;
    const int wave  = threadIdx.x >> 6;
    const int chunk = blockIdx.x * 4 + wave;   // 0..511
    const int gt    = chunk * 64 + lane;
    const int c     = choice[gt];
    int mycnt = 0;
#pragma unroll 1
    for (int e = 0; e < NE; ++e) {
        const unsigned long long m = __ballot(c == e);
        if (lane == e) mycnt = (int)__popcll(m);
    }
    cnt[chunk * 64 + lane] = mycnt;
}

// ---------------------------------------------------------------------------
// K3: exclusive scan of 128 chunk-histograms per group, staged in LDS.
// ---------------------------------------------------------------------------
__global__ __launch_bounds__(256) void k_scan(const int* __restrict__ cnt,
                                              int* __restrict__ off)
{
    __shared__ int s[128 * 64];       // 32 KB
    const int tid  = threadIdx.x;
    const int base = blockIdx.x * 128 * 64;
#pragma unroll
    for (int i = 0; i < 32; ++i)
        s[tid + 256 * i] = cnt[base + tid + 256 * i];
    __syncthreads();
    if (tid < 64) {
        int run = 0;
#pragma unroll 1
        for (int c = 0; c < 128; ++c) {
            const int idx = c * 64 + tid;
            const int v = s[idx];
            s[idx] = run;
            run += v;
        }
    }
    __syncthreads();
#pragma unroll
    for (int i = 0; i < 32; ++i)
        off[base + tid + 256 * i] = s[tid + 256 * i];
}

// ---------------------------------------------------------------------------
// K4: emit expert_index rows (0/1 as fp32) with capacity mask.
// ---------------------------------------------------------------------------
__global__ void k_emit(const int* __restrict__ choice, const int* __restrict__ off,
                       float* __restrict__ eout)
{
    const int lane  = threadIdx.x & 63;
    const int wave  = threadIdx.x >> 6;
    const int chunk = blockIdx.x * 4 + wave;
    const int gt    = chunk * 64 + lane;
    const int c     = choice[gt];
    unsigned long long mymask = 0;
#pragma unroll 1
    for (int e = 0; e < NE; ++e) {
        const unsigned long long m = __ballot(c == e);
        if (c == e) mymask = m;
    }
    const int pre  = (int)__popcll(mymask & ((1ull << lane) - 1ull));
    const int base = off[chunk * 64 + c];
    const float val = (base + pre + 1 <= CAP) ? 1.0f : 0.0f;
    float* op = eout + (size_t)gt * NE;
#pragma unroll
    for (int i = 0; i < 16; ++i) {
        float4 v;
        v.x = (4*i+0 == c) ? val : 0.0f;
        v.y = (4*i+1 == c) ? val : 0.0f;
        v.z = (4*i+2 == c) ? val : 0.0f;
        v.w = (4*i+3 == c) ? val : 0.0f;
        ((float4*)op)[i] = v;
    }
}

// ---------------------------------------------------------------------------
extern "C" void kernel_launch(void* const* d_in, const int* in_sizes, int n_in,
                              void* d_out, int out_size, void* d_ws, size_t ws_size,
                              hipStream_t stream) {
    const float* A = (const float*)d_in[0];   // [4, 8192, 2048]
    const float* W = (const float*)d_in[1];   // [64, 2048]
    const float* b = (const float*)d_in[2];   // [64]

    float* out        = (float*)d_out;
    float* expert_out = out;                        // 2,097,152
    float* probsmax   = out + 2097152;              //    32,768
    float* logits     = out + 2097152 + 32768;      // 2,097,152

    char* ws      = (char*)d_ws;
    int*   choice = (int*)(ws);                 // 128 KB
    int*   idx2   = (int*)(ws + 131072);        // 128 KB
    float* gap    = (float*)(ws + 262144);      // 128 KB
    int*   cnt    = (int*)(ws + 393216);        // 128 KB
    int*   off    = (int*)(ws + 524288);        // 128 KB
    u16*   Wfrag  = (u16*)(ws + 655360);        // 512 KB fragment-major

    hipLaunchKernelGGL(k_wconv, dim3(64), dim3(256), 0, stream, W, Wfrag);
    hipLaunchKernelGGL(k_logits, dim3(1024), dim3(256), 0, stream,
                       A, Wfrag, b, logits, probsmax, choice, idx2, gap);
    hipLaunchKernelGGL(k_refine, dim3(512), dim3(64), 0, stream,
                       A, W, b, choice, idx2, gap);
    hipLaunchKernelGGL(k_count, dim3(128), dim3(256), 0, stream, choice, cnt);
    hipLaunchKernelGGL(k_scan, dim3(4), dim3(256), 0, stream, cnt, off);
    hipLaunchKernelGGL(k_emit, dim3(128), dim3(256), 0, stream, choice, off, expert_out);
}

// Round 11
// 99.442 us; speedup vs baseline: 1.3335x; 1.3335x over previous
//
#include <hip/hip_runtime.h>

#define HID 2048
#define NE 64
#define NTOK 32768        // GROUPS * TOKENS = 4 * 8192
#define CAP 160
#define GAP_THR 0.01f

typedef unsigned short u16;
typedef short bf16x8 __attribute__((ext_vector_type(8)));
typedef float f32x16 __attribute__((ext_vector_type(16)));

typedef __attribute__((address_space(1))) const void gvoid;
typedef __attribute__((address_space(3))) void lvoid;
#define GLOAD_LDS16(gp, lp) \
    __builtin_amdgcn_global_load_lds((gvoid*)(gp), (lvoid*)(lp), 16, 0, 0)

// fp32 -> bf16 hi (truncate) + bf16 lo (truncate of exact remainder).
static __device__ __forceinline__ void cvt8(const float4& a, const float4& b,
                                            bf16x8& hi, bf16x8& lo) {
    float f[8] = {a.x, a.y, a.z, a.w, b.x, b.y, b.z, b.w};
#pragma unroll
    for (int j = 0; j < 8; ++j) {
        const unsigned u = __float_as_uint(f[j]);
        const unsigned h = u >> 16;
        const float r = f[j] - __uint_as_float(h << 16);   // exact
        hi[j] = (short)h;
        lo[j] = (short)(__float_as_uint(r) >> 16);
    }
}

// ---------------------------------------------------------------------------
// K0: split W into bf16 hi/lo, fragment-major: step S (0..127) owns 4KB
// [h0|h1|l0|l1], each chunk 1KB = lane*16B.  S = global K-step = k0/16.
// ---------------------------------------------------------------------------
__global__ void k_wconv(const float* __restrict__ W, u16* __restrict__ Wfrag)
{
    const int idx = blockIdx.x * 256 + threadIdx.x;   // 0..16383
    if (idx >= NE * (HID / 8)) return;
    const int e  = idx >> 8;          // expert 0..63
    const int k0 = (idx & 255) * 8;
    const int S    = k0 >> 4;
    const int khal = (k0 >> 3) & 1;
    const int lane = (e & 31) + khal * 32;

    bf16x8 hi, lo;
    const float4 a = *(const float4*)(W + (size_t)e * HID + k0);
    const float4 b = *(const float4*)(W + (size_t)e * HID + k0 + 4);
    cvt8(a, b, hi, lo);

    u16* base = Wfrag + (size_t)S * 2048 + (size_t)(e >> 5) * 512 + lane * 8;
    *(bf16x8*)(base)        = hi;     // chunk (e>>5)
    *(bf16x8*)(base + 1024) = lo;     // chunk 2+(e>>5)
}

// ---------------------------------------------------------------------------
// K1: logits via 3-term bf16-split MFMA.  64 TOKENS/BLOCK, W THROUGH LDS.
// Block = 512 thr = 8 waves: wave = (kq, et, tt) = (K-half, expert-tile,
// token-tile); each wave owns ONE 32x32 C-quadrant (acc = 16 VGPR).
// Chunk = 64 k: A [64 tok][64 f] = 16 KB + W [4 steps][h0|h1|l0|l1] = 16 KB,
// both via global_load_lds, double-buffered (64 KB -> 2 blocks/CU,
// 16 waves/CU).  W is fetched ONCE per block and shared by all 8 waves via
// LDS -> chip W traffic halves vs 32-token blocks (the round-10 theory:
// the wall scales with total VMEM bytes; W was 2x A).
// Counted vmcnt(4): own-chunk DMA retired, next-chunk stays in flight; only
// the peeled last iter drains.  Two barriers/chunk (land-check + buf-free).
// A source XOR-swizzled (slot = g ^ (row&7)); LDS dest linear (T2/m173).
// k_count is FUSED into the epilogue (wave-0 ballot histogram).
// ---------------------------------------------------------------------------
__global__ __launch_bounds__(512, 4) void k_logits(
    const float* __restrict__ A, const u16* __restrict__ Wfrag,
    const float* __restrict__ bias,
    float* __restrict__ logits, float* __restrict__ probsmax,
    int* __restrict__ choice, int* __restrict__ idx2o, float* __restrict__ gapo,
    int* __restrict__ cnt)
{
    __shared__ char smem_raw[65536];
    float* Abuf = (float*)smem_raw;            // 2 x 4096 floats (32 KB)
    u16*   Wbuf = (u16*)(smem_raw + 32768);    // 2 x 8192 u16   (32 KB)
    float* lacc = (float*)smem_raw;            // epilogue reuse: 2x64x65 fl

    const int tid  = threadIdx.x;
    const int lane = tid & 63;
    const int wv   = __builtin_amdgcn_readfirstlane(tid >> 6);  // 0..7
    const int kq = wv & 1, et = (wv >> 1) & 1, tt = wv >> 2;
    const int tok0 = blockIdx.x * 64;

    // A DMA: wave stages rows [wv*8, +8) in 2 instrs of 4 rows x 256B.
    // lane slot s=lane&15 holds global granule s^(row&7) (LDS stays linear).
    const int s  = lane & 15;
    const int r0 = wv * 8 + (lane >> 4);        // instr 0 rows
    const int r1 = r0 + 4;                       // instr 1 rows
    const float* paA0 = A + (size_t)(tok0 + r0) * HID + ((s ^ (r0 & 7)) << 2);
    const float* paA1 = A + (size_t)(tok0 + r1) * HID + ((s ^ (r1 & 7)) << 2);
    // W DMA: wave stages bytes [wv*2KB, +2KB) of the chunk's 16KB (contiguous)
    const u16* pw0 = Wfrag + wv * 1024 + lane * 8;
    const u16* pw1 = pw0 + 512;

    f32x16 acc;
#pragma unroll
    for (int r = 0; r < 16; ++r) acc[r] = 0.0f;

#define MFMA_ __builtin_amdgcn_mfma_f32_32x32x16_bf16
#define DMA(C) {                                                          \
    const int b_ = (C) & 1;                                               \
    GLOAD_LDS16(paA0 + (C) * 64, Abuf + b_ * 4096 + (wv * 8) * 64);       \
    GLOAD_LDS16(paA1 + (C) * 64, Abuf + b_ * 4096 + (wv * 8 + 4) * 64);   \
    GLOAD_LDS16(pw0 + (size_t)(C) * 8192, Wbuf + b_ * 8192 + wv * 1024);  \
    GLOAD_LDS16(pw1 + (size_t)(C) * 8192, Wbuf + b_ * 8192 + wv * 1024 + 512); }
#define COMPUTE(C) {                                                      \
    const int b_ = (C) & 1;                                               \
    const int trow = tt * 32 + (lane & 31);                               \
    const float* ab = Abuf + b_ * 4096 + trow * 64;                       \
    _Pragma("unroll")                                                     \
    for (int ks = 0; ks < 2; ++ks) {                                      \
        const int g0 = kq * 8 + ks * 4 + (lane >> 5) * 2;                 \
        const float4 va = *(const float4*)(ab + ((g0 ^ (trow & 7)) << 2));\
        const float4 vb = *(const float4*)(ab + (((g0 + 1) ^ (trow & 7)) << 2)); \
        const u16* wp = Wbuf + b_ * 8192 + (kq * 2 + ks) * 2048           \
                      + et * 512 + lane * 8;                              \
        const bf16x8 wh = *(const bf16x8*)(wp);                           \
        const bf16x8 wl = *(const bf16x8*)(wp + 1024);                    \
        bf16x8 ah, al; cvt8(va, vb, ah, al);                              \
        acc = MFMA_(wh, ah, acc, 0, 0, 0);                                \
        acc = MFMA_(wl, ah, acc, 0, 0, 0);                                \
        acc = MFMA_(wh, al, acc, 0, 0, 0);                                \
    } }

    // prologue: chunks 0 and 1 in flight (4 DMA instrs each per wave)
    DMA(0)
    DMA(1)

#pragma unroll 1
    for (int c = 0; c < 31; ++c) {
        asm volatile("s_waitcnt vmcnt(4)" ::: "memory");   // DMA(c) landed
        __builtin_amdgcn_s_barrier();                      // ...for ALL waves
        __builtin_amdgcn_sched_barrier(0);
        COMPUTE(c)
        __builtin_amdgcn_sched_barrier(0);
        __builtin_amdgcn_s_barrier();                      // buf (c&1) free
        if (c < 30) DMA(c + 2)                             // overwrite it
    }
    asm volatile("s_waitcnt vmcnt(0)" ::: "memory");
    __builtin_amdgcn_s_barrier();
    COMPUTE(31)
#undef COMPUTE
#undef DMA

    __syncthreads();                      // staging done; reuse smem as lacc

    // ---- C-quadrant -> lacc[kq][64 tok][65] ----
    {
        const int trow = tt * 32 + (lane & 31);
        float* pl = lacc + kq * 4160 + trow * 65 + et * 32;
#pragma unroll
        for (int r = 0; r < 16; ++r) {
            const int er = (r & 3) + 8 * (r >> 2) + 4 * (lane >> 5);
            pl[er] = acc[r];
        }
    }
    __syncthreads();

    // split-K reduce (+bias), coalesced logits store, stash row into plane 0
    {
        const int t  = tid >> 3;          // 0..63
        const int e0 = (tid & 7) * 8;
        float v[8];
#pragma unroll
        for (int i = 0; i < 8; ++i) {
            const int o = t * 65 + e0 + i;
            v[i] = lacc[o] + lacc[4160 + o] + bias[e0 + i];
        }
        float* lp = logits + (size_t)(tok0 + t) * NE + e0;
        *(float4*)(lp)     = make_float4(v[0], v[1], v[2], v[3]);
        *(float4*)(lp + 4) = make_float4(v[4], v[5], v[6], v[7]);
#pragma unroll
        for (int i = 0; i < 8; ++i) lacc[t * 65 + e0 + i] = v[i];
    }
    __syncthreads();

    // per-token epilogue (wave 0, 64 lanes = 64 tokens): top-2, softmax
    // denominator, and FUSED per-block expert histogram (ballot).
    if (tid < 64) {
        const int t = tid;
        float m1 = -3.4e38f, m2 = -3.4e38f;
        int i1 = 0, i2 = 0;
#pragma unroll
        for (int e = 0; e < NE; ++e) {
            const float vv = lacc[t * 65 + e];
            if (vv > m1)      { m2 = m1; i2 = i1; m1 = vv; i1 = e; }
            else if (vv > m2) { m2 = vv; i2 = e; }
        }
        float sden = 0.0f;
#pragma unroll
        for (int e = 0; e < NE; ++e)
            sden += __expf(lacc[t * 65 + e] - m1);
        const int g2 = tok0 + t;
        probsmax[g2] = 1.0f / sden;       // max prob = exp(0)/sum
        choice[g2]   = i1;
        idx2o[g2]    = i2;
        gapo[g2]     = m1 - m2;

        int mycnt = 0;
#pragma unroll 1
        for (int e = 0; e < NE; ++e) {
            const unsigned long long m = __ballot(i1 == e);
            if (tid == e) mycnt = (int)__popcll(m);
        }
        cnt[blockIdx.x * 64 + tid] = mycnt;
    }
}

// ---------------------------------------------------------------------------
// K1b: fp64 refinement of near-tie argmax, wave-cooperative.
// ---------------------------------------------------------------------------
__global__ __launch_bounds__(64) void k_refine(
    const float* __restrict__ A, const float* __restrict__ W,
    const float* __restrict__ bias,
    int* __restrict__ choice, const int* __restrict__ idx2,
    const float* __restrict__ gap)
{
    const int lane = threadIdx.x;
    const int gt0  = blockIdx.x * 64;
    const int gtl  = gt0 + lane;
    const bool flag = (gap[gtl] < GAP_THR) && (choice[gtl] != idx2[gtl]);
    unsigned long long m = __ballot(flag);
    while (m) {
        const int t = (int)__ffsll((long long)m) - 1;
        m &= m - 1;
        const int gt = gt0 + t;
        const int i1 = choice[gt], i2 = idx2[gt];
        const float* a  = A + (size_t)gt * HID;
        const float* w1 = W + (size_t)i1 * HID;
        const float* w2 = W + (size_t)i2 * HID;
        double d1 = 0.0, d2 = 0.0;
#pragma unroll 4
        for (int h = lane; h < HID; h += 64) {
            const double av = (double)a[h];
            d1 += av * (double)w1[h];
            d2 += av * (double)w2[h];
        }
#pragma unroll
        for (int o = 32; o; o >>= 1) {
            d1 += __shfl_xor(d1, o);
            d2 += __shfl_xor(d2, o);
        }
        if (lane == 0) {
            d1 += (double)bias[i1];
            d2 += (double)bias[i2];
            if (d2 > d1 || (d2 == d1 && i2 < i1)) choice[gt] = i2;
        }
    }
}

// ---------------------------------------------------------------------------
// K3: exclusive scan of 128 chunk-histograms per group, staged in LDS.
// (chunk = 64 tokens = one k_logits block; 512 chunks total, 128/group)
// ---------------------------------------------------------------------------
__global__ __launch_bounds__(256) void k_scan(const int* __restrict__ cnt,
                                              int* __restrict__ off)
{
    __shared__ int s[128 * 64];       // 32 KB
    const int tid  = threadIdx.x;
    const int base = blockIdx.x * 128 * 64;
#pragma unroll
    for (int i = 0; i < 32; ++i)
        s[tid + 256 * i] = cnt[base + tid + 256 * i];
    __syncthreads();
    if (tid < 64) {
        int run = 0;
#pragma unroll 1
        for (int c = 0; c < 128; ++c) {
            const int idx = c * 64 + tid;
            const int v = s[idx];
            s[idx] = run;
            run += v;
        }
    }
    __syncthreads();
#pragma unroll
    for (int i = 0; i < 32; ++i)
        off[base + tid + 256 * i] = s[tid + 256 * i];
}

// ---------------------------------------------------------------------------
// K4: emit expert_index rows (0/1 as fp32) with capacity mask.
// ---------------------------------------------------------------------------
__global__ void k_emit(const int* __restrict__ choice, const int* __restrict__ off,
                       float* __restrict__ eout)
{
    const int lane  = threadIdx.x & 63;
    const int wave  = threadIdx.x >> 6;
    const int chunk = blockIdx.x * 4 + wave;
    const int gt    = chunk * 64 + lane;
    const int c     = choice[gt];
    unsigned long long mymask = 0;
#pragma unroll 1
    for (int e = 0; e < NE; ++e) {
        const unsigned long long m = __ballot(c == e);
        if (c == e) mymask = m;
    }
    const int pre  = (int)__popcll(mymask & ((1ull << lane) - 1ull));
    const int base = off[chunk * 64 + c];
    const float val = (base + pre + 1 <= CAP) ? 1.0f : 0.0f;
    float* op = eout + (size_t)gt * NE;
#pragma unroll
    for (int i = 0; i < 16; ++i) {
        float4 v;
        v.x = (4*i+0 == c) ? val : 0.0f;
        v.y = (4*i+1 == c) ? val : 0.0f;
        v.z = (4*i+2 == c) ? val : 0.0f;
        v.w = (4*i+3 == c) ? val : 0.0f;
        ((float4*)op)[i] = v;
    }
}

// ---------------------------------------------------------------------------
extern "C" void kernel_launch(void* const* d_in, const int* in_sizes, int n_in,
                              void* d_out, int out_size, void* d_ws, size_t ws_size,
                              hipStream_t stream) {
    const float* A = (const float*)d_in[0];   // [4, 8192, 2048]
    const float* W = (const float*)d_in[1];   // [64, 2048]
    const float* b = (const float*)d_in[2];   // [64]

    float* out        = (float*)d_out;
    float* expert_out = out;                        // 2,097,152
    float* probsmax   = out + 2097152;              //    32,768
    float* logits     = out + 2097152 + 32768;      // 2,097,152

    char* ws      = (char*)d_ws;
    int*   choice = (int*)(ws);                 // 128 KB
    int*   idx2   = (int*)(ws + 131072);        // 128 KB
    float* gap    = (float*)(ws + 262144);      // 128 KB
    int*   cnt    = (int*)(ws + 393216);        // 128 KB
    int*   off    = (int*)(ws + 524288);        // 128 KB
    u16*   Wfrag  = (u16*)(ws + 655360);        // 512 KB fragment-major

    hipLaunchKernelGGL(k_wconv, dim3(64), dim3(256), 0, stream, W, Wfrag);
    hipLaunchKernelGGL(k_logits, dim3(512), dim3(512), 0, stream,
                       A, Wfrag, b, logits, probsmax, choice, idx2, gap, cnt);
    hipLaunchKernelGGL(k_refine, dim3(512), dim3(64), 0, stream,
                       A, W, b, choice, idx2, gap);
    hipLaunchKernelGGL(k_scan, dim3(4), dim3(256), 0, stream, cnt, off);
    hipLaunchKernelGGL(k_emit, dim3(128), dim3(256), 0, stream, choice, off, expert_out);
}